// Round 1
// baseline (94.537 us; speedup 1.0000x reference)
//
#include <hip/hip_runtime.h>
#include <math.h>

// Problem constants (from setup_inputs): B=4, T=8, C=3, H=W=256, D_MODEL=32, HEADS=4
constexpr int TT = 8;
constexpr int CC = 3;
constexpr int DM = 32;
constexpr int NH = 4;
constexpr int HW = 256 * 256;

// Algebraic collapse (see session journal):
//   x_s = W_in z_s + b_in                     (affine in z_s, 3 inputs)
//   q7[o]  = qb0[o] + QW[o][c] z7[c]          QW = W_q W_in, qb0 = b_q + W_q b_in
//   k_s[o] = kb0[o] + KW[o][c] z_s[c]
//   sc[n][s] = qb[n] + qw[n][c] z_s[c]        (head-n score, scaled by 1/sqrt(8))
//     qw[n][c] = A[n][c] + M[n][c][c2] z7[c2] M = sum_{o in n} QW[o][c2] KW[o][c]
//     qb[n]    = B0[n]   + N[n][c] z7[c]
//   softmax weights w[s] sum to 1 =>
//   y_c = yb2[c] + sum_n sum_c2 G[c][n][c2] * wz[n][c2],  wz[n][c]=sum_s w[s] z_s[c]
//     G[c][n][c2] = sum_i (sum_{o in n} W_o[c][o] W_v[o][i]) W_in[i][c2]
//     yb2[c]      = b_o[c] + sum_o W_o[c][o] (b_v[o] + sum_i W_v[o][i] b_in[i])

__global__ __launch_bounds__(256) void attn_fused(
    const float* __restrict__ z,
    const float* __restrict__ W_in, const float* __restrict__ b_in,
    const float* __restrict__ W_q,  const float* __restrict__ b_q,
    const float* __restrict__ W_k,  const float* __restrict__ b_k,
    const float* __restrict__ W_v,  const float* __restrict__ b_v,
    const float* __restrict__ W_o,  const float* __restrict__ b_o,
    float* __restrict__ out)
{
    // Stage-1 intermediates
    __shared__ float sQW[DM][CC], sKW[DM][CC];
    __shared__ float sqb0[DM], skb0[DM];
    __shared__ float sWoV[CC][NH][DM];
    __shared__ float sbv2[DM];
    // Stage-2 final constants (103 floats)
    __shared__ float sM[NH][CC][CC], sA[NH][CC], sN[NH][CC], sB0[NH];
    __shared__ float sG[CC][NH][CC], syb2[CC];

    const int tid = threadIdx.x;

    // ---------------- stage 1: weight-weight products ----------------
    if (tid < 96) {
        int o = tid / 3, c = tid % 3;
        float a = 0.f;
        #pragma unroll
        for (int i = 0; i < DM; ++i) a += W_q[o*DM+i] * W_in[i*CC+c];
        sQW[o][c] = a;
    } else if (tid < 192) {
        int t = tid - 96, o = t / 3, c = t % 3;
        float a = 0.f;
        #pragma unroll
        for (int i = 0; i < DM; ++i) a += W_k[o*DM+i] * W_in[i*CC+c];
        sKW[o][c] = a;
    } else if (tid < 224) {
        int o = tid - 192;
        float a = b_q[o];
        #pragma unroll
        for (int i = 0; i < DM; ++i) a += W_q[o*DM+i] * b_in[i];
        sqb0[o] = a;
    } else {
        int o = tid - 224;
        float a = b_k[o];
        #pragma unroll
        for (int i = 0; i < DM; ++i) a += W_k[o*DM+i] * b_in[i];
        skb0[o] = a;
    }
    for (int e = tid; e < CC*NH*DM + DM; e += 256) {
        if (e < CC*NH*DM) {
            int c = e >> 7, n = (e >> 5) & 3, i = e & 31;
            float a = 0.f;
            #pragma unroll
            for (int j = 0; j < 8; ++j)
                a += W_o[c*DM + n*8 + j] * W_v[(n*8+j)*DM + i];
            sWoV[c][n][i] = a;
        } else {
            int o = e - CC*NH*DM;
            float a = b_v[o];
            #pragma unroll
            for (int i = 0; i < DM; ++i) a += W_v[o*DM+i] * b_in[i];
            sbv2[o] = a;
        }
    }
    __syncthreads();

    // ---------------- stage 2: fold into 103 pixel-loop constants ----------------
    const float scale = 0.35355339059327373f;  // 1/sqrt(DK=8)
    if (tid < 36) {
        int n = tid / 9, r = tid % 9, c = r / 3, c2 = r % 3;
        float a = 0.f;
        #pragma unroll
        for (int j = 0; j < 8; ++j) a += sQW[n*8+j][c2] * sKW[n*8+j][c];
        sM[n][c][c2] = scale * a;
    } else if (tid < 48) {
        int idx = tid - 36, n = idx / 3, c = idx % 3;
        float a = 0.f;
        #pragma unroll
        for (int j = 0; j < 8; ++j) a += sqb0[n*8+j] * sKW[n*8+j][c];
        sA[n][c] = scale * a;
    } else if (tid < 60) {
        int idx = tid - 48, n = idx / 3, c2 = idx % 3;
        float a = 0.f;
        #pragma unroll
        for (int j = 0; j < 8; ++j) a += sQW[n*8+j][c2] * skb0[n*8+j];
        sN[n][c2] = scale * a;
    } else if (tid < 64) {
        int n = tid - 60;
        float a = 0.f;
        #pragma unroll
        for (int j = 0; j < 8; ++j) a += sqb0[n*8+j] * skb0[n*8+j];
        sB0[n] = scale * a;
    } else if (tid < 100) {
        int idx = tid - 64, c = idx / 12, r = idx % 12, n = r / 3, c2 = r % 3;
        float a = 0.f;
        #pragma unroll
        for (int i = 0; i < DM; ++i) a += sWoV[c][n][i] * W_in[i*CC+c2];
        sG[c][n][c2] = a;
    } else if (tid < 103) {
        int c = tid - 100;
        float a = b_o[c];
        #pragma unroll
        for (int o = 0; o < DM; ++o) a += W_o[c*DM+o] * sbv2[o];
        syb2[c] = a;
    }
    __syncthreads();

    // ---------------- per-pixel main path ----------------
    const int p  = blockIdx.x * 256 + tid;     // global pixel id
    const int hw = p & (HW - 1);
    const int b  = p >> 16;
    const float* zb = z + (size_t)b * TT * CC * HW + hw;

    float zv[TT][CC];
    #pragma unroll
    for (int s = 0; s < TT; ++s)
        #pragma unroll
        for (int c = 0; c < CC; ++c)
            zv[s][c] = zb[(s*CC + c) * HW];   // coalesced: lane = w

    // q-side constants for this pixel (affine in z7)
    float qw[NH][CC], qb[NH];
    #pragma unroll
    for (int n = 0; n < NH; ++n) {
        qb[n] = sB0[n] + sN[n][0]*zv[7][0] + sN[n][1]*zv[7][1] + sN[n][2]*zv[7][2];
        #pragma unroll
        for (int c = 0; c < CC; ++c)
            qw[n][c] = sA[n][c] + sM[n][c][0]*zv[7][0] + sM[n][c][1]*zv[7][1] + sM[n][c][2]*zv[7][2];
    }

    // per-head softmax over s=0..7, accumulate wz[n][c] = sum_s w[s] z_s[c]
    float wz[NH][CC];
    #pragma unroll
    for (int n = 0; n < NH; ++n) {
        float sc[TT];
        float m = -1e30f;
        #pragma unroll
        for (int s = 0; s < TT; ++s) {
            float v = qb[n] + qw[n][0]*zv[s][0] + qw[n][1]*zv[s][1] + qw[n][2]*zv[s][2];
            sc[s] = v;
            m = fmaxf(m, v);
        }
        float l = 0.f;
        #pragma unroll
        for (int s = 0; s < TT; ++s) { float e = __expf(sc[s] - m); sc[s] = e; l += e; }
        float inv = 1.f / l;
        #pragma unroll
        for (int c = 0; c < CC; ++c) {
            float a = 0.f;
            #pragma unroll
            for (int s = 0; s < TT; ++s) a += sc[s] * zv[s][c];
            wz[n][c] = a * inv;
        }
    }

    // output projection
    #pragma unroll
    for (int c = 0; c < CC; ++c) {
        float a = syb2[c];
        #pragma unroll
        for (int n = 0; n < NH; ++n)
            #pragma unroll
            for (int c2 = 0; c2 < CC; ++c2)
                a += sG[c][n][c2] * wz[n][c2];
        out[((size_t)b * CC + c) * HW + hw] = a;   // (B,3,H,W), coalesced
    }
}

extern "C" void kernel_launch(void* const* d_in, const int* in_sizes, int n_in,
                              void* d_out, int out_size, void* d_ws, size_t ws_size,
                              hipStream_t stream) {
    const float* z    = (const float*)d_in[0];
    const float* W_in = (const float*)d_in[1];
    const float* b_in = (const float*)d_in[2];
    const float* W_q  = (const float*)d_in[3];
    const float* b_q  = (const float*)d_in[4];
    const float* W_k  = (const float*)d_in[5];
    const float* b_k  = (const float*)d_in[6];
    const float* W_v  = (const float*)d_in[7];
    const float* b_v  = (const float*)d_in[8];
    const float* W_o  = (const float*)d_in[9];
    const float* b_o  = (const float*)d_in[10];
    float* out = (float*)d_out;

    const int B = in_sizes[0] / (TT * CC * HW);   // = 4
    const int npix = B * HW;
    const int blocks = npix / 256;                // 1024

    attn_fused<<<blocks, 256, 0, stream>>>(
        z, W_in, b_in, W_q, b_q, W_k, b_k, W_v, b_v, W_o, b_o, out);
}